// Round 3
// baseline (8479.112 us; speedup 1.0000x reference)
//
#include <hip/hip_runtime.h>
#include <hip/hip_bf16.h>
#include <math.h>

// Problem constants
#define BB 64
#define SS 256
#define SP 257           // S+1
#define DD 768
#define FF 3072
#define HH 12
#define DKK 64
#define ROWS (BB*SP)     // 16448 = 257*64
#define MCONV (BB*SS)    // 16384
#define RB ((size_t)ROWS * DD)   // 12,632,064 elems

typedef short bf16x8 __attribute__((ext_vector_type(8)));
typedef float f32x4 __attribute__((ext_vector_type(4)));
typedef unsigned short ushort8v __attribute__((ext_vector_type(8)));

// ---------------- bf16 helpers ----------------
__device__ __forceinline__ ushort f2bf(float x) {
    union { __hip_bfloat16 h; ushort u; } c;
    c.h = __float2bfloat16(x);
    return c.u;
}
__device__ __forceinline__ float bf2f(ushort u) {
    union { __hip_bfloat16 h; ushort u; } c;
    c.u = u;
    return __bfloat162float(c.h);
}

__device__ __forceinline__ float gelu_tanh_f(float x) {
    float x3 = x * x * x;
    float u = 0.7978845608028654f * (x + 0.044715f * x3);
    return 0.5f * x * (1.0f + tanhf(u));
}

template <bool IS_MAX>
__device__ __forceinline__ float blk_reduce(float v, float* red4) {
    #pragma unroll
    for (int o = 32; o > 0; o >>= 1) {
        float other = __shfl_down(v, o, 64);
        v = IS_MAX ? fmaxf(v, other) : (v + other);
    }
    __syncthreads();
    if ((threadIdx.x & 63) == 0) red4[threadIdx.x >> 6] = v;
    __syncthreads();
    if (IS_MAX) return fmaxf(fmaxf(red4[0], red4[1]), fmaxf(red4[2], red4[3]));
    return red4[0] + red4[1] + red4[2] + red4[3];
}

// ---------------- weight transpose + f32->bf16: W[K][N] -> Wt[N][K] ----------------
__global__ __launch_bounds__(256) void wt_kernel(
    const float* __restrict__ W, ushort* __restrict__ Wt, int K, int N)
{
    __shared__ float tile[32][33];
    const int k0 = blockIdx.x * 32, n0 = blockIdx.y * 32;
    const int t = threadIdx.x;
    {
        const int r = t >> 3, c4 = (t & 7) * 4;
        float4 v = *reinterpret_cast<const float4*>(&W[(size_t)(k0 + r) * N + n0 + c4]);
        tile[r][c4 + 0] = v.x; tile[r][c4 + 1] = v.y;
        tile[r][c4 + 2] = v.z; tile[r][c4 + 3] = v.w;
    }
    __syncthreads();
    {
        const int n = t >> 3, k4 = (t & 7) * 4;
        ushort4 o;
        o.x = f2bf(tile[k4 + 0][n]); o.y = f2bf(tile[k4 + 1][n]);
        o.z = f2bf(tile[k4 + 2][n]); o.w = f2bf(tile[k4 + 3][n]);
        *reinterpret_cast<ushort4*>(&Wt[(size_t)(n0 + n) * K + k0 + k4]) = o;
    }
}

// ---------------- MFMA GEMM: C[M,N] = A[M,K] @ Bt[N,K]^T + bias (+gelu) ----------------
// BM=64, BN=128, BK=64. 256 threads = 4 waves, wave -> 32x64 subtile (2x4 frags).
// A: f32 or bf16 row-major; Bt: bf16 row-major [N][K]; C: f32 or bf16.
// M%64==0, N%128==0, K%64==0.
template <bool A_F32, bool C_BF16, bool GELU>
__global__ __launch_bounds__(256) void mfma_gemm(
    const void* __restrict__ Ap, const ushort* __restrict__ Bt,
    const float* __restrict__ bias, void* __restrict__ Cp,
    int M, int N, int K)
{
    __shared__ ushort As[64][72];    // +8 pad: row stride 144B = 36 banks (mod 32 = 4)
    __shared__ ushort Bs[128][72];
    const int tid = threadIdx.x;
    const int lane = tid & 63, wave = tid >> 6;
    const int wr = wave & 1, wc = wave >> 1;
    const int row0 = blockIdx.y * 64, col0 = blockIdx.x * 128;

    f32x4 acc[2][4];
    #pragma unroll
    for (int m = 0; m < 2; ++m)
        #pragma unroll
        for (int n = 0; n < 4; ++n)
            acc[m][n] = (f32x4){0.f, 0.f, 0.f, 0.f};

    const int arow = tid >> 2, akq = (tid & 3) * 16;   // A: 4 thr/row x 16 k
    const int brow = tid >> 1, bkh = (tid & 1) * 32;   // B: 2 thr/row x 32 k

    for (int k0 = 0; k0 < K; k0 += 64) {
        if (A_F32) {
            const float* A = (const float*)Ap;
            const float* src = &A[(size_t)(row0 + arow) * K + k0 + akq];
            float4 v0 = *reinterpret_cast<const float4*>(src + 0);
            float4 v1 = *reinterpret_cast<const float4*>(src + 4);
            float4 v2 = *reinterpret_cast<const float4*>(src + 8);
            float4 v3 = *reinterpret_cast<const float4*>(src + 12);
            ushort8v u0, u1;
            u0[0]=f2bf(v0.x); u0[1]=f2bf(v0.y); u0[2]=f2bf(v0.z); u0[3]=f2bf(v0.w);
            u0[4]=f2bf(v1.x); u0[5]=f2bf(v1.y); u0[6]=f2bf(v1.z); u0[7]=f2bf(v1.w);
            u1[0]=f2bf(v2.x); u1[1]=f2bf(v2.y); u1[2]=f2bf(v2.z); u1[3]=f2bf(v2.w);
            u1[4]=f2bf(v3.x); u1[5]=f2bf(v3.y); u1[6]=f2bf(v3.z); u1[7]=f2bf(v3.w);
            *reinterpret_cast<ushort8v*>(&As[arow][akq]) = u0;
            *reinterpret_cast<ushort8v*>(&As[arow][akq + 8]) = u1;
        } else {
            const ushort* A = (const ushort*)Ap;
            const ushort* src = &A[(size_t)(row0 + arow) * K + k0 + akq];
            *reinterpret_cast<ushort8v*>(&As[arow][akq]) =
                *reinterpret_cast<const ushort8v*>(src);
            *reinterpret_cast<ushort8v*>(&As[arow][akq + 8]) =
                *reinterpret_cast<const ushort8v*>(src + 8);
        }
        {
            const ushort* src = &Bt[(size_t)(col0 + brow) * K + k0 + bkh];
            #pragma unroll
            for (int j = 0; j < 4; ++j)
                *reinterpret_cast<ushort8v*>(&Bs[brow][bkh + 8 * j]) =
                    *reinterpret_cast<const ushort8v*>(src + 8 * j);
        }
        __syncthreads();
        #pragma unroll
        for (int ks = 0; ks < 2; ++ks) {
            bf16x8 af[2], bfr[4];
            #pragma unroll
            for (int m = 0; m < 2; ++m)
                af[m] = *reinterpret_cast<const bf16x8*>(
                    &As[wr * 32 + m * 16 + (lane & 15)][ks * 32 + (lane >> 4) * 8]);
            #pragma unroll
            for (int n = 0; n < 4; ++n)
                bfr[n] = *reinterpret_cast<const bf16x8*>(
                    &Bs[wc * 64 + n * 16 + (lane & 15)][ks * 32 + (lane >> 4) * 8]);
            #pragma unroll
            for (int m = 0; m < 2; ++m)
                #pragma unroll
                for (int n = 0; n < 4; ++n)
                    acc[m][n] = __builtin_amdgcn_mfma_f32_16x16x32_bf16(
                        af[m], bfr[n], acc[m][n], 0, 0, 0);
        }
        __syncthreads();
    }

    // epilogue: C/D layout col=lane&15, row=(lane>>4)*4+j  [m89/m91 verified]
    #pragma unroll
    for (int m = 0; m < 2; ++m) {
        #pragma unroll
        for (int n = 0; n < 4; ++n) {
            const int col = col0 + wc * 64 + n * 16 + (lane & 15);
            const float bcol = bias[col];
            #pragma unroll
            for (int j = 0; j < 4; ++j) {
                const int row = row0 + wr * 32 + m * 16 + (lane >> 4) * 4 + j;
                float v = acc[m][n][j] + bcol;
                if (GELU) v = gelu_tanh_f(v);
                if (C_BF16) ((ushort*)Cp)[(size_t)row * N + col] = f2bf(v);
                else        ((float*)Cp)[(size_t)row * N + col] = v;
            }
        }
    }
}

// ---------------- build h (f32): masking + pos_emb + agg token; mask_pos ----------------
__global__ __launch_bounds__(256) void build_h_kernel(
    const float* __restrict__ emb, const float* __restrict__ rnd3,
    const int* __restrict__ perm, const float* __restrict__ pos_emb,
    const float* __restrict__ mask_tok, const float* __restrict__ agg_tok,
    float* __restrict__ h, float* __restrict__ mask_pos)
{
    const int sf = blockIdx.x;   // 0..256
    const int b = blockIdx.y;    // 0..63
    const int t = threadIdx.x;
    float* hrow = h + ((size_t)b * SP + sf) * DD;
    if (sf == 0) {
        #pragma unroll
        for (int i = 0; i < 3; ++i) hrow[t + 256 * i] = agg_tok[t + 256 * i];
        return;
    }
    const int s = sf - 1;
    const int idx = b * SS + s;
    const float r0 = rnd3[idx * 3 + 0];
    const float r1 = rnd3[idx * 3 + 1];
    const float r2 = rnd3[idx * 3 + 2];
    const bool sel = (r0 <= 0.2f);
    const float m  = (sel && r1 <= 0.8f) ? 1.f : 0.f;
    const float rn = (sel && r1 > 0.8f && r2 <= 0.5f) ? 1.f : 0.f;
    const float nt = (sel && r1 > 0.8f && r2 > 0.5f) ? 1.f : 0.f;
    if (t == 0) mask_pos[idx] = m + rn + nt;
    const int p = perm[idx];
    const float* xrow = emb + (size_t)idx * DD;
    const float* srow = emb + (size_t)p * DD;
    const float keep = 1.f - m - rn;
    #pragma unroll
    for (int i = 0; i < 3; ++i) {
        const int c = t + 256 * i;
        hrow[c] = xrow[c] * keep + mask_tok[c] * m + srow[c] * rn + pos_emb[s * DD + c];
    }
}

// ---------------- fused attention (bf16 q,k,v -> bf16 o), per (b,h,q) ----------------
__global__ __launch_bounds__(256) void attn_kernel(
    const ushort* __restrict__ Q, const ushort* __restrict__ K,
    const ushort* __restrict__ V, ushort* __restrict__ O)
{
    const int qi = blockIdx.x;   // 0..256
    const int hh = blockIdx.y;   // 0..11
    const int b  = blockIdx.z;   // 0..63
    const int t  = threadIdx.x;
    __shared__ float qs[64];
    __shared__ float sc[257];
    __shared__ float red4[4];
    __shared__ float pv[256];

    const size_t base = ((size_t)b * SP) * DD + hh * DKK;
    if (t < 64) qs[t] = bf2f(Q[base + (size_t)qi * DD + t]);
    __syncthreads();

    for (int k = t; k < SP; k += 256) {
        const ushort* kr = &K[base + (size_t)k * DD];
        float s = 0.f;
        #pragma unroll
        for (int j8 = 0; j8 < 8; ++j8) {
            ushort8v kv = *reinterpret_cast<const ushort8v*>(kr + 8 * j8);
            #pragma unroll
            for (int i = 0; i < 8; ++i) s += qs[8 * j8 + i] * bf2f(kv[i]);
        }
        sc[k] = s * 0.125f;
    }
    float lm = -3.4e38f;
    for (int k = t; k < SP; k += 256) lm = fmaxf(lm, sc[k]);
    const float mx = blk_reduce<true>(lm, red4);
    float ls = 0.f;
    for (int k = t; k < SP; k += 256) {
        float e = __expf(sc[k] - mx);
        sc[k] = e;
        ls += e;
    }
    const float ssum = blk_reduce<false>(ls, red4);
    const float inv = 1.f / ssum;

    const int d = t & 63, kc = t >> 6;
    float part = 0.f;
    for (int k = kc; k < SP; k += 4) part += sc[k] * bf2f(V[base + (size_t)k * DD + d]);
    pv[t] = part;
    __syncthreads();
    if (t < 64) {
        const float o = (pv[t] + pv[t + 64] + pv[t + 128] + pv[t + 192]) * inv;
        O[base + (size_t)qi * DD + t] = f2bf(o);
    }
}

// ---------------- h = LayerNorm(h + r) * g + b (h f32, r bf16) ----------------
__global__ __launch_bounds__(256) void add_ln_kernel(
    float* __restrict__ h, const ushort* __restrict__ r,
    const float* __restrict__ g, const float* __restrict__ bta)
{
    const int row = blockIdx.x;
    const int t = threadIdx.x;
    __shared__ float red4[4];
    float* hp = h + (size_t)row * DD;
    const ushort* rp = r + (size_t)row * DD;
    const float x0 = hp[t]       + bf2f(rp[t]);
    const float x1 = hp[t + 256] + bf2f(rp[t + 256]);
    const float x2 = hp[t + 512] + bf2f(rp[t + 512]);
    const float s = blk_reduce<false>(x0 + x1 + x2, red4);
    const float mu = s * (1.f / 768.f);
    const float d0 = x0 - mu, d1 = x1 - mu, d2 = x2 - mu;
    const float v = blk_reduce<false>(d0 * d0 + d1 * d1 + d2 * d2, red4);
    const float inv = rsqrtf(v * (1.f / 768.f) + 1e-6f);
    hp[t]       = d0 * inv * g[t]       + bta[t];
    hp[t + 256] = d1 * inv * g[t + 256] + bta[t + 256];
    hp[t + 512] = d2 * inv * g[t + 512] + bta[t + 512];
}

// ---------------- final outputs ----------------
__global__ __launch_bounds__(256) void out_copy_kernel(
    const float* __restrict__ h, float* __restrict__ agg, float* __restrict__ pred)
{
    const int sf = blockIdx.x;  // 0..256
    const int b = blockIdx.y;
    const int t = threadIdx.x;
    const float* hp = h + ((size_t)b * SP + sf) * DD;
    if (sf == 0) {
        #pragma unroll
        for (int i = 0; i < 3; ++i) agg[(size_t)b * DD + t + 256 * i] = hp[t + 256 * i];
    } else {
        float* pp = pred + ((size_t)(b * SS + sf - 1)) * DD;
        #pragma unroll
        for (int i = 0; i < 3; ++i) pp[t + 256 * i] = hp[t + 256 * i];
    }
}

// ---------------- host launch ----------------
extern "C" void kernel_launch(void* const* d_in, const int* in_sizes, int n_in,
                              void* d_out, int out_size, void* d_ws, size_t ws_size,
                              hipStream_t stream)
{
    const float* inputs   = (const float*)d_in[0];
    const float* rnd3     = (const float*)d_in[1];
    const int*   perm     = (const int*)d_in[2];
    const float* conv_w   = (const float*)d_in[3];
    const float* conv_b   = (const float*)d_in[4];
    const float* pos_emb  = (const float*)d_in[5];
    const float* mask_tok = (const float*)d_in[6];
    const float* agg_tok  = (const float*)d_in[7];
    const float* wq = (const float*)d_in[8];
    const float* bq = (const float*)d_in[9];
    const float* wk = (const float*)d_in[10];
    const float* bk = (const float*)d_in[11];
    const float* wv = (const float*)d_in[12];
    const float* bv = (const float*)d_in[13];
    const float* wo = (const float*)d_in[14];
    const float* bo = (const float*)d_in[15];
    const float* ln1_g = (const float*)d_in[16];
    const float* ln1_b = (const float*)d_in[17];
    const float* w1 = (const float*)d_in[18];
    const float* b1 = (const float*)d_in[19];
    const float* w2 = (const float*)d_in[20];
    const float* b2 = (const float*)d_in[21];
    const float* ln2_g = (const float*)d_in[22];
    const float* ln2_b = (const float*)d_in[23];

    float* out = (float*)d_out;
    float* agg_out  = out;
    float* pred_out = out + 49152;
    float* mask_out = out + 49152 + 12582912;
    float* emb_out  = out + 49152 + 12582912 + 16384;

    // ---- workspace layout (~206 MB total) ----
    // h (f32 RB) | qb kb vb ob (bf16 RB each; mid[ROWS*FF bf16] aliases qkvo
    // exactly: 4*RB = ROWS*FF) | rbuf (bf16 RB) | bf16 weights (29.1 MB)
    char* base = (char*)d_ws;
    float*  h    = (float*)base;
    ushort* qb   = (ushort*)(base + RB * 4);
    ushort* kb   = qb + RB;
    ushort* vb   = kb + RB;
    ushort* ob   = vb + RB;
    ushort* mid  = qb;               // alias: ROWS*FF == 4*RB
    ushort* rbuf = ob + RB;
    ushort* wptr = rbuf + RB;

    ushort* convT = wptr;                          wptr += (size_t)DD * 512;
    ushort* wqT[2]; ushort* wkT[2]; ushort* wvT[2]; ushort* woT[2];
    ushort* w1T[2]; ushort* w2T[2];
    for (int l = 0; l < 2; ++l) {
        wqT[l] = wptr; wptr += (size_t)DD * DD;
        wkT[l] = wptr; wptr += (size_t)DD * DD;
        wvT[l] = wptr; wptr += (size_t)DD * DD;
        woT[l] = wptr; wptr += (size_t)DD * DD;
        w1T[l] = wptr; wptr += (size_t)DD * FF;
        w2T[l] = wptr; wptr += (size_t)FF * DD;
    }

    const dim3 blk(256);

    // 0. weight transposes (f32 -> bf16 [N][K])
    wt_kernel<<<dim3(512 / 32, DD / 32), blk, 0, stream>>>(conv_w, convT, 512, DD);
    for (int l = 0; l < 2; ++l) {
        wt_kernel<<<dim3(DD / 32, DD / 32), blk, 0, stream>>>(wq + (size_t)l*DD*DD, wqT[l], DD, DD);
        wt_kernel<<<dim3(DD / 32, DD / 32), blk, 0, stream>>>(wk + (size_t)l*DD*DD, wkT[l], DD, DD);
        wt_kernel<<<dim3(DD / 32, DD / 32), blk, 0, stream>>>(wv + (size_t)l*DD*DD, wvT[l], DD, DD);
        wt_kernel<<<dim3(DD / 32, DD / 32), blk, 0, stream>>>(wo + (size_t)l*DD*DD, woT[l], DD, DD);
        wt_kernel<<<dim3(DD / 32, FF / 32), blk, 0, stream>>>(w1 + (size_t)l*DD*FF, w1T[l], DD, FF);
        wt_kernel<<<dim3(FF / 32, DD / 32), blk, 0, stream>>>(w2 + (size_t)l*FF*DD, w2T[l], FF, DD);
    }

    // 1. conv as GEMM -> embeddings (f32, direct to d_out)
    mfma_gemm<true, false, false><<<dim3(DD / 128, MCONV / 64), blk, 0, stream>>>(
        inputs, convT, conv_b, emb_out, MCONV, DD, 512);

    // 2. build h + mask_pos
    build_h_kernel<<<dim3(SP, BB), blk, 0, stream>>>(
        emb_out, rnd3, perm, pos_emb, mask_tok, agg_tok, h, mask_out);

    // 3. transformer layers
    for (int l = 0; l < 2; ++l) {
        mfma_gemm<true, true, false><<<dim3(DD / 128, ROWS / 64), blk, 0, stream>>>(
            h, wqT[l], bq + l * DD, qb, ROWS, DD, DD);
        mfma_gemm<true, true, false><<<dim3(DD / 128, ROWS / 64), blk, 0, stream>>>(
            h, wkT[l], bk + l * DD, kb, ROWS, DD, DD);
        mfma_gemm<true, true, false><<<dim3(DD / 128, ROWS / 64), blk, 0, stream>>>(
            h, wvT[l], bv + l * DD, vb, ROWS, DD, DD);

        attn_kernel<<<dim3(SP, HH, BB), blk, 0, stream>>>(qb, kb, vb, ob);

        mfma_gemm<false, true, false><<<dim3(DD / 128, ROWS / 64), blk, 0, stream>>>(
            ob, woT[l], bo + l * DD, rbuf, ROWS, DD, DD);

        add_ln_kernel<<<dim3(ROWS), blk, 0, stream>>>(h, rbuf, ln1_g + l * DD, ln1_b + l * DD);

        // FFN (mid aliases q/k/v/o — all dead here)
        mfma_gemm<true, true, true><<<dim3(FF / 128, ROWS / 64), blk, 0, stream>>>(
            h, w1T[l], b1 + l * FF, mid, ROWS, FF, DD);
        mfma_gemm<false, true, false><<<dim3(DD / 128, ROWS / 64), blk, 0, stream>>>(
            mid, w2T[l], b2 + l * DD, rbuf, ROWS, DD, FF);

        add_ln_kernel<<<dim3(ROWS), blk, 0, stream>>>(h, rbuf, ln2_g + l * DD, ln2_b + l * DD);
    }

    // 4. outputs
    out_copy_kernel<<<dim3(SP, BB), blk, 0, stream>>>(h, agg_out, pred_out);
}

// Round 5
// 1641.992 us; speedup vs baseline: 5.1639x; 5.1639x over previous
//
#include <hip/hip_runtime.h>
#include <hip/hip_bf16.h>
#include <math.h>

// Problem constants
#define BB 64
#define SS 256
#define SP 257           // S+1
#define DD 768
#define FF 3072
#define HH 12
#define DKK 64
#define ROWS (BB*SP)     // 16448 = 257*64
#define MCONV (BB*SS)    // 16384
#define RB ((size_t)ROWS * DD)   // 12,632,064 elems

typedef short bf16x8 __attribute__((ext_vector_type(8)));
typedef float f32x4 __attribute__((ext_vector_type(4)));
typedef unsigned short ushort8v __attribute__((ext_vector_type(8)));

// ---------------- bf16 helpers ----------------
__device__ __forceinline__ ushort f2bf(float x) {
    union { __hip_bfloat16 h; ushort u; } c;
    c.h = __float2bfloat16(x);
    return c.u;
}
__device__ __forceinline__ float bf2f(ushort u) {
    union { __hip_bfloat16 h; ushort u; } c;
    c.u = u;
    return __bfloat162float(c.h);
}

__device__ __forceinline__ float gelu_tanh_f(float x) {
    float x3 = x * x * x;
    float u = 0.7978845608028654f * (x + 0.044715f * x3);
    return 0.5f * x * (1.0f + tanhf(u));
}

template <bool IS_MAX>
__device__ __forceinline__ float blk_reduce(float v, float* red4) {
    #pragma unroll
    for (int o = 32; o > 0; o >>= 1) {
        float other = __shfl_down(v, o, 64);
        v = IS_MAX ? fmaxf(v, other) : (v + other);
    }
    __syncthreads();
    if ((threadIdx.x & 63) == 0) red4[threadIdx.x >> 6] = v;
    __syncthreads();
    if (IS_MAX) return fmaxf(fmaxf(red4[0], red4[1]), fmaxf(red4[2], red4[3]));
    return red4[0] + red4[1] + red4[2] + red4[3];
}

// ---------------- weight transpose + f32->bf16: W[K][N] -> Wt[N][K] ----------------
__global__ __launch_bounds__(256) void wt_kernel(
    const float* __restrict__ W, ushort* __restrict__ Wt, int K, int N)
{
    __shared__ float tile[32][33];
    const int k0 = blockIdx.x * 32, n0 = blockIdx.y * 32;
    const int t = threadIdx.x;
    {
        const int r = t >> 3, c4 = (t & 7) * 4;
        float4 v = *reinterpret_cast<const float4*>(&W[(size_t)(k0 + r) * N + n0 + c4]);
        tile[r][c4 + 0] = v.x; tile[r][c4 + 1] = v.y;
        tile[r][c4 + 2] = v.z; tile[r][c4 + 3] = v.w;
    }
    __syncthreads();
    {
        const int n = t >> 3, k4 = (t & 7) * 4;
        ushort4 o;
        o.x = f2bf(tile[k4 + 0][n]); o.y = f2bf(tile[k4 + 1][n]);
        o.z = f2bf(tile[k4 + 2][n]); o.w = f2bf(tile[k4 + 3][n]);
        *reinterpret_cast<ushort4*>(&Wt[(size_t)(n0 + n) * K + k0 + k4]) = o;
    }
}

// ---------------- MFMA GEMM: C[M,N] = A[M,K] @ Bt[N,K]^T + bias (+gelu) ----------------
template <bool A_F32, bool C_BF16, bool GELU>
__global__ __launch_bounds__(256) void mfma_gemm(
    const void* __restrict__ Ap, const ushort* __restrict__ Bt,
    const float* __restrict__ bias, void* __restrict__ Cp,
    int M, int N, int K)
{
    __shared__ ushort As[64][72];
    __shared__ ushort Bs[128][72];
    const int tid = threadIdx.x;
    const int lane = tid & 63, wave = tid >> 6;
    const int wr = wave & 1, wc = wave >> 1;
    const int row0 = blockIdx.y * 64, col0 = blockIdx.x * 128;

    f32x4 acc[2][4];
    #pragma unroll
    for (int m = 0; m < 2; ++m)
        #pragma unroll
        for (int n = 0; n < 4; ++n)
            acc[m][n] = (f32x4){0.f, 0.f, 0.f, 0.f};

    const int arow = tid >> 2, akq = (tid & 3) * 16;
    const int brow = tid >> 1, bkh = (tid & 1) * 32;

    for (int k0 = 0; k0 < K; k0 += 64) {
        if (A_F32) {
            const float* A = (const float*)Ap;
            const float* src = &A[(size_t)(row0 + arow) * K + k0 + akq];
            float4 v0 = *reinterpret_cast<const float4*>(src + 0);
            float4 v1 = *reinterpret_cast<const float4*>(src + 4);
            float4 v2 = *reinterpret_cast<const float4*>(src + 8);
            float4 v3 = *reinterpret_cast<const float4*>(src + 12);
            ushort8v u0, u1;
            u0[0]=f2bf(v0.x); u0[1]=f2bf(v0.y); u0[2]=f2bf(v0.z); u0[3]=f2bf(v0.w);
            u0[4]=f2bf(v1.x); u0[5]=f2bf(v1.y); u0[6]=f2bf(v1.z); u0[7]=f2bf(v1.w);
            u1[0]=f2bf(v2.x); u1[1]=f2bf(v2.y); u1[2]=f2bf(v2.z); u1[3]=f2bf(v2.w);
            u1[4]=f2bf(v3.x); u1[5]=f2bf(v3.y); u1[6]=f2bf(v3.z); u1[7]=f2bf(v3.w);
            *reinterpret_cast<ushort8v*>(&As[arow][akq]) = u0;
            *reinterpret_cast<ushort8v*>(&As[arow][akq + 8]) = u1;
        } else {
            const ushort* A = (const ushort*)Ap;
            const ushort* src = &A[(size_t)(row0 + arow) * K + k0 + akq];
            *reinterpret_cast<ushort8v*>(&As[arow][akq]) =
                *reinterpret_cast<const ushort8v*>(src);
            *reinterpret_cast<ushort8v*>(&As[arow][akq + 8]) =
                *reinterpret_cast<const ushort8v*>(src + 8);
        }
        {
            const ushort* src = &Bt[(size_t)(col0 + brow) * K + k0 + bkh];
            #pragma unroll
            for (int j = 0; j < 4; ++j)
                *reinterpret_cast<ushort8v*>(&Bs[brow][bkh + 8 * j]) =
                    *reinterpret_cast<const ushort8v*>(src + 8 * j);
        }
        __syncthreads();
        #pragma unroll
        for (int ks = 0; ks < 2; ++ks) {
            bf16x8 af[2], bfr[4];
            #pragma unroll
            for (int m = 0; m < 2; ++m)
                af[m] = *reinterpret_cast<const bf16x8*>(
                    &As[wr * 32 + m * 16 + (lane & 15)][ks * 32 + (lane >> 4) * 8]);
            #pragma unroll
            for (int n = 0; n < 4; ++n)
                bfr[n] = *reinterpret_cast<const bf16x8*>(
                    &Bs[wc * 64 + n * 16 + (lane & 15)][ks * 32 + (lane >> 4) * 8]);
            #pragma unroll
            for (int m = 0; m < 2; ++m)
                #pragma unroll
                for (int n = 0; n < 4; ++n)
                    acc[m][n] = __builtin_amdgcn_mfma_f32_16x16x32_bf16(
                        af[m], bfr[n], acc[m][n], 0, 0, 0);
        }
        __syncthreads();
    }

    #pragma unroll
    for (int m = 0; m < 2; ++m) {
        #pragma unroll
        for (int n = 0; n < 4; ++n) {
            const int col = col0 + wc * 64 + n * 16 + (lane & 15);
            const float bcol = bias[col];
            #pragma unroll
            for (int j = 0; j < 4; ++j) {
                const int row = row0 + wr * 32 + m * 16 + (lane >> 4) * 4 + j;
                float v = acc[m][n][j] + bcol;
                if (GELU) v = gelu_tanh_f(v);
                if (C_BF16) ((ushort*)Cp)[(size_t)row * N + col] = f2bf(v);
                else        ((float*)Cp)[(size_t)row * N + col] = v;
            }
        }
    }
}

// ---------------- build h (f32) ----------------
__global__ __launch_bounds__(256) void build_h_kernel(
    const float* __restrict__ emb, const float* __restrict__ rnd3,
    const int* __restrict__ perm, const float* __restrict__ pos_emb,
    const float* __restrict__ mask_tok, const float* __restrict__ agg_tok,
    float* __restrict__ h, float* __restrict__ mask_pos)
{
    const int sf = blockIdx.x;
    const int b = blockIdx.y;
    const int t = threadIdx.x;
    float* hrow = h + ((size_t)b * SP + sf) * DD;
    if (sf == 0) {
        #pragma unroll
        for (int i = 0; i < 3; ++i) hrow[t + 256 * i] = agg_tok[t + 256 * i];
        return;
    }
    const int s = sf - 1;
    const int idx = b * SS + s;
    const float r0 = rnd3[idx * 3 + 0];
    const float r1 = rnd3[idx * 3 + 1];
    const float r2 = rnd3[idx * 3 + 2];
    const bool sel = (r0 <= 0.2f);
    const float m  = (sel && r1 <= 0.8f) ? 1.f : 0.f;
    const float rn = (sel && r1 > 0.8f && r2 <= 0.5f) ? 1.f : 0.f;
    const float nt = (sel && r1 > 0.8f && r2 > 0.5f) ? 1.f : 0.f;
    if (t == 0) mask_pos[idx] = m + rn + nt;
    const int p = perm[idx];
    const float* xrow = emb + (size_t)idx * DD;
    const float* srow = emb + (size_t)p * DD;
    const float keep = 1.f - m - rn;
    #pragma unroll
    for (int i = 0; i < 3; ++i) {
        const int c = t + 256 * i;
        hrow[c] = xrow[c] * keep + mask_tok[c] * m + srow[c] * rn + pos_emb[s * DD + c];
    }
}

// ---------------- V transpose per (b,h): V[257][64] -> Vt[64][288] (zero-padded) ----------------
__global__ __launch_bounds__(256) void vt_kernel(
    const ushort* __restrict__ V, ushort* __restrict__ Vt)
{
    const int bh = blockIdx.x;
    const int b = bh / HH, h = bh % HH;
    const int t = threadIdx.x;
    __shared__ ushort tile[64][65];
    const size_t vtb = (size_t)bh * 64 * 288;
    const int d = t & 63, kk = t >> 6;
    const int kq = t & 63, dg = t >> 6;
    for (int kt = 0; kt < 5; ++kt) {
        #pragma unroll
        for (int i = 0; i < 16; ++i) {
            const int r = kk + 4 * i;
            const int kg = kt * 64 + r;
            tile[r][d] = (kg < SP) ? V[((size_t)b * SP + kg) * DD + h * 64 + d] : (ushort)0;
        }
        __syncthreads();
        #pragma unroll
        for (int i = 0; i < 16; ++i) {
            const int dd2 = dg + 4 * i;
            const int k = kt * 64 + kq;
            if (k < 288) Vt[vtb + (size_t)dd2 * 288 + k] = tile[kq][dd2];
        }
        __syncthreads();
    }
}

// ---------------- MFMA flash attention: block per (b,h), 4 waves x 16 q-rows ----------------
__global__ __launch_bounds__(256) void attn_mfma(
    const ushort* __restrict__ Q, const ushort* __restrict__ K,
    const ushort* __restrict__ Vt, ushort* __restrict__ O)
{
    const int h = blockIdx.x, b = blockIdx.y;
    const int t = threadIdx.x, lane = t & 63, w = t >> 6;
    const int lg = lane >> 4, lr = lane & 15;
    __shared__ ushort Pl[4][16][296];   // per-wave P tile, stride 296 (16B-aligned rows)

    const size_t qkbase = ((size_t)b * SP) * DD + (size_t)h * DKK;
    const size_t vtbase = (size_t)(b * HH + h) * 64 * 288;

    // zero the k=272..287 pad once (only cols 0..271 are rewritten per pass)
    #pragma unroll
    for (int i = 0; i < 4; ++i) Pl[w][lr][272 + lg * 4 + i] = 0;

    for (int p = 0; p < 5; ++p) {
        const int q0 = p * 64 + w * 16;
        const int qr = min(q0 + lr, SP - 1);
        bf16x8 aq0 = *reinterpret_cast<const bf16x8*>(&Q[qkbase + (size_t)qr * DD + lg * 8]);
        bf16x8 aq1 = *reinterpret_cast<const bf16x8*>(&Q[qkbase + (size_t)qr * DD + 32 + lg * 8]);

        // ---- scores S[16 q][272 k] via MFMA, K B-frags straight from global ----
        f32x4 sc[17];
        #pragma unroll
        for (int n = 0; n < 17; ++n) {
            const int kr = min(n * 16 + lr, SP - 1);
            const ushort* kp = &K[qkbase + (size_t)kr * DD + lg * 8];
            bf16x8 bk0 = *reinterpret_cast<const bf16x8*>(kp);
            bf16x8 bk1 = *reinterpret_cast<const bf16x8*>(kp + 32);
            f32x4 a = (f32x4){0.f, 0.f, 0.f, 0.f};
            a = __builtin_amdgcn_mfma_f32_16x16x32_bf16(aq0, bk0, a, 0, 0, 0);
            a = __builtin_amdgcn_mfma_f32_16x16x32_bf16(aq1, bk1, a, 0, 0, 0);
            sc[n] = a;
        }

        // ---- mask + scale, row max ----
        float rmax[4] = {-1e30f, -1e30f, -1e30f, -1e30f};
        #pragma unroll
        for (int n = 0; n < 17; ++n) {
            const int kcol = n * 16 + lr;
            if (kcol >= SP) {
                sc[n] = (f32x4){-1e30f, -1e30f, -1e30f, -1e30f};
            } else {
                sc[n] *= 0.125f;
            }
            #pragma unroll
            for (int j = 0; j < 4; ++j) rmax[j] = fmaxf(rmax[j], sc[n][j]);
        }
        #pragma unroll
        for (int msk = 1; msk <= 8; msk <<= 1)
            #pragma unroll
            for (int j = 0; j < 4; ++j)
                rmax[j] = fmaxf(rmax[j], __shfl_xor(rmax[j], msk, 64));

        // ---- exp + row sum + write P (bf16) to LDS ----
        float rsum[4] = {0.f, 0.f, 0.f, 0.f};
        #pragma unroll
        for (int n = 0; n < 17; ++n) {
            #pragma unroll
            for (int j = 0; j < 4; ++j) {
                const float e = __expf(sc[n][j] - rmax[j]);
                rsum[j] += e;
                Pl[w][lg * 4 + j][n * 16 + lr] = f2bf(e);
            }
        }
        #pragma unroll
        for (int msk = 1; msk <= 8; msk <<= 1)
            #pragma unroll
            for (int j = 0; j < 4; ++j)
                rsum[j] += __shfl_xor(rsum[j], msk, 64);

        __syncthreads();

        // ---- PV: O[16 q][64 d], P A-frags from LDS, Vt B-frags from global ----
        f32x4 o[4];
        #pragma unroll
        for (int dn = 0; dn < 4; ++dn) o[dn] = (f32x4){0.f, 0.f, 0.f, 0.f};
        #pragma unroll
        for (int kb = 0; kb < 9; ++kb) {
            bf16x8 pa = *reinterpret_cast<const bf16x8*>(&Pl[w][lr][kb * 32 + lg * 8]);
            #pragma unroll
            for (int dn = 0; dn < 4; ++dn) {
                bf16x8 bv = *reinterpret_cast<const bf16x8*>(
                    &Vt[vtbase + (size_t)(dn * 16 + lr) * 288 + kb * 32 + lg * 8]);
                o[dn] = __builtin_amdgcn_mfma_f32_16x16x32_bf16(pa, bv, o[dn], 0, 0, 0);
            }
        }

        // ---- store (rows in C layout == rsum rows) ----
        float rinv[4];
        #pragma unroll
        for (int j = 0; j < 4; ++j) rinv[j] = 1.f / rsum[j];
        #pragma unroll
        for (int dn = 0; dn < 4; ++dn) {
            #pragma unroll
            for (int j = 0; j < 4; ++j) {
                const int q = q0 + lg * 4 + j;
                if (q < SP)
                    O[qkbase + (size_t)q * DD + dn * 16 + lr] = f2bf(o[dn][j] * rinv[j]);
            }
        }
        __syncthreads();
    }
}

// ---------------- h = LayerNorm(h + r) * g + b (h f32, r bf16) ----------------
__global__ __launch_bounds__(256) void add_ln_kernel(
    float* __restrict__ h, const ushort* __restrict__ r,
    const float* __restrict__ g, const float* __restrict__ bta)
{
    const int row = blockIdx.x;
    const int t = threadIdx.x;
    __shared__ float red4[4];
    float* hp = h + (size_t)row * DD;
    const ushort* rp = r + (size_t)row * DD;
    const float x0 = hp[t]       + bf2f(rp[t]);
    const float x1 = hp[t + 256] + bf2f(rp[t + 256]);
    const float x2 = hp[t + 512] + bf2f(rp[t + 512]);
    const float s = blk_reduce<false>(x0 + x1 + x2, red4);
    const float mu = s * (1.f / 768.f);
    const float d0 = x0 - mu, d1 = x1 - mu, d2 = x2 - mu;
    const float v = blk_reduce<false>(d0 * d0 + d1 * d1 + d2 * d2, red4);
    const float inv = rsqrtf(v * (1.f / 768.f) + 1e-6f);
    hp[t]       = d0 * inv * g[t]       + bta[t];
    hp[t + 256] = d1 * inv * g[t + 256] + bta[t + 256];
    hp[t + 512] = d2 * inv * g[t + 512] + bta[t + 512];
}

// ---------------- final outputs ----------------
__global__ __launch_bounds__(256) void out_copy_kernel(
    const float* __restrict__ h, float* __restrict__ agg, float* __restrict__ pred)
{
    const int sf = blockIdx.x;
    const int b = blockIdx.y;
    const int t = threadIdx.x;
    const float* hp = h + ((size_t)b * SP + sf) * DD;
    if (sf == 0) {
        #pragma unroll
        for (int i = 0; i < 3; ++i) agg[(size_t)b * DD + t + 256 * i] = hp[t + 256 * i];
    } else {
        float* pp = pred + ((size_t)(b * SS + sf - 1)) * DD;
        #pragma unroll
        for (int i = 0; i < 3; ++i) pp[t + 256 * i] = hp[t + 256 * i];
    }
}

// ---------------- host launch ----------------
extern "C" void kernel_launch(void* const* d_in, const int* in_sizes, int n_in,
                              void* d_out, int out_size, void* d_ws, size_t ws_size,
                              hipStream_t stream)
{
    const float* inputs   = (const float*)d_in[0];
    const float* rnd3     = (const float*)d_in[1];
    const int*   perm     = (const int*)d_in[2];
    const float* conv_w   = (const float*)d_in[3];
    const float* conv_b   = (const float*)d_in[4];
    const float* pos_emb  = (const float*)d_in[5];
    const float* mask_tok = (const float*)d_in[6];
    const float* agg_tok  = (const float*)d_in[7];
    const float* wq = (const float*)d_in[8];
    const float* bq = (const float*)d_in[9];
    const float* wk = (const float*)d_in[10];
    const float* bk = (const float*)d_in[11];
    const float* wv = (const float*)d_in[12];
    const float* bv = (const float*)d_in[13];
    const float* wo = (const float*)d_in[14];
    const float* bo = (const float*)d_in[15];
    const float* ln1_g = (const float*)d_in[16];
    const float* ln1_b = (const float*)d_in[17];
    const float* w1 = (const float*)d_in[18];
    const float* b1 = (const float*)d_in[19];
    const float* w2 = (const float*)d_in[20];
    const float* b2 = (const float*)d_in[21];
    const float* ln2_g = (const float*)d_in[22];
    const float* ln2_b = (const float*)d_in[23];

    float* out = (float*)d_out;
    float* agg_out  = out;
    float* pred_out = out + 49152;
    float* mask_out = out + 49152 + 12582912;
    float* emb_out  = out + 49152 + 12582912 + 16384;

    // ---- workspace layout (~209 MB) ----
    // h f32 (4RB bytes) | qb kb vb ob (bf16 RB each; FFN mid aliases all 4) |
    // vt (768*64*288 bf16 = 28.3 MB; doubles as post-attn residual buffer rbuf) |
    // bf16 weights (29.1 MB)
    char* base = (char*)d_ws;
    float*  h    = (float*)base;
    ushort* qb   = (ushort*)(base + RB * 4);
    ushort* kb   = qb + RB;
    ushort* vb   = kb + RB;
    ushort* ob   = vb + RB;
    ushort* mid  = qb;                       // alias: ROWS*FF == 4*RB
    ushort* vt   = ob + RB;                  // 768*64*288 = 14,155,776 elems
    ushort* rbuf = vt;                       // alias (vt dead when rbuf in use)
    ushort* wptr = vt + (size_t)768 * 64 * 288;

    ushort* convT = wptr;                          wptr += (size_t)DD * 512;
    ushort* wqT[2]; ushort* wkT[2]; ushort* wvT[2]; ushort* woT[2];
    ushort* w1T[2]; ushort* w2T[2];
    for (int l = 0; l < 2; ++l) {
        wqT[l] = wptr; wptr += (size_t)DD * DD;
        wkT[l] = wptr; wptr += (size_t)DD * DD;
        wvT[l] = wptr; wptr += (size_t)DD * DD;
        woT[l] = wptr; wptr += (size_t)DD * DD;
        w1T[l] = wptr; wptr += (size_t)DD * FF;
        w2T[l] = wptr; wptr += (size_t)FF * DD;
    }

    const dim3 blk(256);

    // 0. weight transposes (f32 -> bf16 [N][K])
    wt_kernel<<<dim3(512 / 32, DD / 32), blk, 0, stream>>>(conv_w, convT, 512, DD);
    for (int l = 0; l < 2; ++l) {
        wt_kernel<<<dim3(DD / 32, DD / 32), blk, 0, stream>>>(wq + (size_t)l*DD*DD, wqT[l], DD, DD);
        wt_kernel<<<dim3(DD / 32, DD / 32), blk, 0, stream>>>(wk + (size_t)l*DD*DD, wkT[l], DD, DD);
        wt_kernel<<<dim3(DD / 32, DD / 32), blk, 0, stream>>>(wv + (size_t)l*DD*DD, wvT[l], DD, DD);
        wt_kernel<<<dim3(DD / 32, DD / 32), blk, 0, stream>>>(wo + (size_t)l*DD*DD, woT[l], DD, DD);
        wt_kernel<<<dim3(DD / 32, FF / 32), blk, 0, stream>>>(w1 + (size_t)l*DD*FF, w1T[l], DD, FF);
        wt_kernel<<<dim3(FF / 32, DD / 32), blk, 0, stream>>>(w2 + (size_t)l*FF*DD, w2T[l], FF, DD);
    }

    // 1. conv as GEMM -> embeddings (f32, direct to d_out)
    mfma_gemm<true, false, false><<<dim3(DD / 128, MCONV / 64), blk, 0, stream>>>(
        inputs, convT, conv_b, emb_out, MCONV, DD, 512);

    // 2. build h + mask_pos
    build_h_kernel<<<dim3(SP, BB), blk, 0, stream>>>(
        emb_out, rnd3, perm, pos_emb, mask_tok, agg_tok, h, mask_out);

    // 3. transformer layers
    for (int l = 0; l < 2; ++l) {
        mfma_gemm<true, true, false><<<dim3(DD / 128, ROWS / 64), blk, 0, stream>>>(
            h, wqT[l], bq + l * DD, qb, ROWS, DD, DD);
        mfma_gemm<true, true, false><<<dim3(DD / 128, ROWS / 64), blk, 0, stream>>>(
            h, wkT[l], bk + l * DD, kb, ROWS, DD, DD);
        mfma_gemm<true, true, false><<<dim3(DD / 128, ROWS / 64), blk, 0, stream>>>(
            h, wvT[l], bv + l * DD, vb, ROWS, DD, DD);

        vt_kernel<<<dim3(BB * HH), blk, 0, stream>>>(vb, vt);
        attn_mfma<<<dim3(HH, BB), blk, 0, stream>>>(qb, kb, vt, ob);

        // O-projection -> rbuf (aliases vt, which is dead now)
        mfma_gemm<false, true, false><<<dim3(DD / 128, ROWS / 64), blk, 0, stream>>>(
            ob, woT[l], bo + l * DD, rbuf, ROWS, DD, DD);

        add_ln_kernel<<<dim3(ROWS), blk, 0, stream>>>(h, rbuf, ln1_g + l * DD, ln1_b + l * DD);

        // FFN (mid aliases q/k/v/o — all dead here)
        mfma_gemm<true, true, true><<<dim3(FF / 128, ROWS / 64), blk, 0, stream>>>(
            h, w1T[l], b1 + l * FF, mid, ROWS, FF, DD);
        mfma_gemm<false, true, false><<<dim3(DD / 128, ROWS / 64), blk, 0, stream>>>(
            mid, w2T[l], b2 + l * DD, rbuf, ROWS, DD, FF);

        add_ln_kernel<<<dim3(ROWS), blk, 0, stream>>>(h, rbuf, ln2_g + l * DD, ln2_b + l * DD);
    }

    // 4. outputs
    out_copy_kernel<<<dim3(SP, BB), blk, 0, stream>>>(h, agg_out, pred_out);
}

// Round 6
// 1599.472 us; speedup vs baseline: 5.3012x; 1.0266x over previous
//
#include <hip/hip_runtime.h>
#include <hip/hip_bf16.h>
#include <math.h>

// Problem constants
#define BB 64
#define SS 256
#define SP 257           // S+1
#define DD 768
#define FF 3072
#define HH 12
#define DKK 64
#define ROWS (BB*SP)     // 16448 = 257*64
#define MPAD 16512       // 129*128 (M padded to 128 for gemm128)
#define MCONV (BB*SS)    // 16384 = 128*128
#define RB ((size_t)ROWS * DD)     // 12,632,064
#define PRB ((size_t)MPAD * DD)    // 12,681,216

typedef short bf16x8 __attribute__((ext_vector_type(8)));
typedef float f32x4 __attribute__((ext_vector_type(4)));
typedef unsigned short ushort8v __attribute__((ext_vector_type(8)));

// ---------------- bf16 helpers ----------------
__device__ __forceinline__ ushort f2bf(float x) {
    union { __hip_bfloat16 h; ushort u; } c;
    c.h = __float2bfloat16(x);
    return c.u;
}
__device__ __forceinline__ float bf2f(ushort u) {
    union { __hip_bfloat16 h; ushort u; } c;
    c.u = u;
    return __bfloat162float(c.h);
}

__device__ __forceinline__ float gelu_tanh_f(float x) {
    float x3 = x * x * x;
    float u = 0.7978845608028654f * (x + 0.044715f * x3);
    return 0.5f * x * (1.0f + tanhf(u));
}

// async global->LDS, 16B per lane; l must be the wave-uniform base
__device__ __forceinline__ void gload16(const ushort* g, ushort* l) {
    __builtin_amdgcn_global_load_lds(
        (__attribute__((address_space(1))) void*)(g),
        (__attribute__((address_space(3))) void*)(l), 16, 0, 0);
}

template <bool IS_MAX>
__device__ __forceinline__ float blk_reduce(float v, float* red4) {
    #pragma unroll
    for (int o = 32; o > 0; o >>= 1) {
        float other = __shfl_down(v, o, 64);
        v = IS_MAX ? fmaxf(v, other) : (v + other);
    }
    __syncthreads();
    if ((threadIdx.x & 63) == 0) red4[threadIdx.x >> 6] = v;
    __syncthreads();
    if (IS_MAX) return fmaxf(fmaxf(red4[0], red4[1]), fmaxf(red4[2], red4[3]));
    return red4[0] + red4[1] + red4[2] + red4[3];
}

// ---------------- inputs f32 -> bf16 (conv A) ----------------
__global__ __launch_bounds__(256) void conv_in_bf_kernel(
    const float* __restrict__ in, ushort* __restrict__ out)
{
    const size_t i = ((size_t)blockIdx.x * 256 + threadIdx.x) * 4;
    float4 v = *reinterpret_cast<const float4*>(&in[i]);
    ushort4 o;
    o.x = f2bf(v.x); o.y = f2bf(v.y); o.z = f2bf(v.z); o.w = f2bf(v.w);
    *reinterpret_cast<ushort4*>(&out[i]) = o;
}

// ---------------- weight transpose + f32->bf16: W[K][N] -> Wt[N][K] ----------------
__global__ __launch_bounds__(256) void wt_kernel(
    const float* __restrict__ W, ushort* __restrict__ Wt, int K, int N)
{
    __shared__ float tile[32][33];
    const int k0 = blockIdx.x * 32, n0 = blockIdx.y * 32;
    const int t = threadIdx.x;
    {
        const int r = t >> 3, c4 = (t & 7) * 4;
        float4 v = *reinterpret_cast<const float4*>(&W[(size_t)(k0 + r) * N + n0 + c4]);
        tile[r][c4 + 0] = v.x; tile[r][c4 + 1] = v.y;
        tile[r][c4 + 2] = v.z; tile[r][c4 + 3] = v.w;
    }
    __syncthreads();
    {
        const int n = t >> 3, k4 = (t & 7) * 4;
        ushort4 o;
        o.x = f2bf(tile[k4 + 0][n]); o.y = f2bf(tile[k4 + 1][n]);
        o.z = f2bf(tile[k4 + 2][n]); o.w = f2bf(tile[k4 + 3][n]);
        *reinterpret_cast<ushort4*>(&Wt[(size_t)(n0 + n) * K + k0 + k4]) = o;
    }
}

// ---------------- gemm128: C[M,N] = A[M,K] @ Bt[N,K]^T + bias (+gelu) ----------------
// m97 structure: 128x128 tile, BK=64, global_load_lds(16B) staging, linear LDS.
// 256 thr = 4 waves (2x2), wave -> 64x64 (4x4 frags of 16x16x32).
// A,Bt bf16 row-major; M%128==0, N%128==0, K%64==0.
template <bool C_BF16, bool GELU>
__global__ __launch_bounds__(256) void gemm128(
    const ushort* __restrict__ A, const ushort* __restrict__ Bt,
    const float* __restrict__ bias, void* __restrict__ Cp,
    int M, int N, int K)
{
    __shared__ ushort As[128 * 64];   // linear [128][64]
    __shared__ ushort Bs[128 * 64];
    const int tid = threadIdx.x;
    const int lane = tid & 63, w = tid >> 6;
    const int wr = w & 1, wc = w >> 1;
    const int lg = lane >> 4, lr = lane & 15;
    const int row0 = blockIdx.y * 128, col0 = blockIdx.x * 128;

    f32x4 acc[4][4];
    #pragma unroll
    for (int m = 0; m < 4; ++m)
        #pragma unroll
        for (int n = 0; n < 4; ++n)
            acc[m][n] = (f32x4){0.f, 0.f, 0.f, 0.f};

    // staging geometry: per round r (4 rounds per tile), wave w stages 8 rows:
    //   row = r*32 + w*8 + lane/8, col(ushort) = (lane&7)*8   (16B per lane)
    //   LDS base (wave-uniform) = r*2048 + w*512
    const int g_rowoff = w * 8 + (lane >> 3);
    const int g_colu   = (lane & 7) * 8;

    for (int k0 = 0; k0 < K; k0 += 64) {
        #pragma unroll
        for (int r = 0; r < 4; ++r) {
            const int row = r * 32 + g_rowoff;
            gload16(&A[(size_t)(row0 + row) * K + k0 + g_colu],
                    &As[r * 2048 + w * 512]);
            gload16(&Bt[(size_t)(col0 + row) * K + k0 + g_colu],
                    &Bs[r * 2048 + w * 512]);
        }
        __syncthreads();   // drains vmcnt + barrier

        #pragma unroll
        for (int ks = 0; ks < 2; ++ks) {
            bf16x8 af[4], bf[4];
            #pragma unroll
            for (int m = 0; m < 4; ++m)
                af[m] = *reinterpret_cast<const bf16x8*>(
                    &As[(wr * 64 + m * 16 + lr) * 64 + ks * 32 + lg * 8]);
            #pragma unroll
            for (int n = 0; n < 4; ++n)
                bf[n] = *reinterpret_cast<const bf16x8*>(
                    &Bs[(wc * 64 + n * 16 + lr) * 64 + ks * 32 + lg * 8]);
            #pragma unroll
            for (int m = 0; m < 4; ++m)
                #pragma unroll
                for (int n = 0; n < 4; ++n)
                    acc[m][n] = __builtin_amdgcn_mfma_f32_16x16x32_bf16(
                        af[m], bf[n], acc[m][n], 0, 0, 0);
        }
        __syncthreads();
    }

    // epilogue: C/D layout col=lane&15, row=(lane>>4)*4+j (verified r3/r5)
    #pragma unroll
    for (int m = 0; m < 4; ++m) {
        #pragma unroll
        for (int n = 0; n < 4; ++n) {
            const int col = col0 + wc * 64 + n * 16 + lr;
            const float bcol = bias[col];
            #pragma unroll
            for (int j = 0; j < 4; ++j) {
                const int row = row0 + wr * 64 + m * 16 + lg * 4 + j;
                float v = acc[m][n][j] + bcol;
                if (GELU) v = gelu_tanh_f(v);
                if (C_BF16) ((ushort*)Cp)[(size_t)row * N + col] = f2bf(v);
                else        ((float*)Cp)[(size_t)row * N + col] = v;
            }
        }
    }
}

// ---------------- build h (f32 + bf16 shadow) ----------------
__global__ __launch_bounds__(256) void build_h_kernel(
    const float* __restrict__ emb, const float* __restrict__ rnd3,
    const int* __restrict__ perm, const float* __restrict__ pos_emb,
    const float* __restrict__ mask_tok, const float* __restrict__ agg_tok,
    float* __restrict__ h, ushort* __restrict__ hb, float* __restrict__ mask_pos)
{
    const int sf = blockIdx.x;
    const int b = blockIdx.y;
    const int t = threadIdx.x;
    const size_t ro = ((size_t)b * SP + sf) * DD;
    float* hrow = h + ro;
    ushort* hbrow = hb + ro;
    if (sf == 0) {
        #pragma unroll
        for (int i = 0; i < 3; ++i) {
            const float v = agg_tok[t + 256 * i];
            hrow[t + 256 * i] = v;
            hbrow[t + 256 * i] = f2bf(v);
        }
        return;
    }
    const int s = sf - 1;
    const int idx = b * SS + s;
    const float r0 = rnd3[idx * 3 + 0];
    const float r1 = rnd3[idx * 3 + 1];
    const float r2 = rnd3[idx * 3 + 2];
    const bool sel = (r0 <= 0.2f);
    const float m  = (sel && r1 <= 0.8f) ? 1.f : 0.f;
    const float rn = (sel && r1 > 0.8f && r2 <= 0.5f) ? 1.f : 0.f;
    const float nt = (sel && r1 > 0.8f && r2 > 0.5f) ? 1.f : 0.f;
    if (t == 0) mask_pos[idx] = m + rn + nt;
    const int p = perm[idx];
    const float* xrow = emb + (size_t)idx * DD;
    const float* srow = emb + (size_t)p * DD;
    const float keep = 1.f - m - rn;
    #pragma unroll
    for (int i = 0; i < 3; ++i) {
        const int c = t + 256 * i;
        const float v = xrow[c] * keep + mask_tok[c] * m + srow[c] * rn + pos_emb[s * DD + c];
        hrow[c] = v;
        hbrow[c] = f2bf(v);
    }
}

// ---------------- V transpose per (b,h): V[257][64] -> Vt[64][288] (zero-padded) ----------------
__global__ __launch_bounds__(256) void vt_kernel(
    const ushort* __restrict__ V, ushort* __restrict__ Vt)
{
    const int bh = blockIdx.x;
    const int b = bh / HH, h = bh % HH;
    const int t = threadIdx.x;
    __shared__ ushort tile[64][65];
    const size_t vtb = (size_t)bh * 64 * 288;
    const int d = t & 63, kk = t >> 6;
    const int kq = t & 63, dg = t >> 6;
    for (int kt = 0; kt < 5; ++kt) {
        #pragma unroll
        for (int i = 0; i < 16; ++i) {
            const int r = kk + 4 * i;
            const int kg = kt * 64 + r;
            tile[r][d] = (kg < SP) ? V[((size_t)b * SP + kg) * DD + h * 64 + d] : (ushort)0;
        }
        __syncthreads();
        #pragma unroll
        for (int i = 0; i < 16; ++i) {
            const int dd2 = dg + 4 * i;
            const int k = kt * 64 + kq;
            if (k < 288) Vt[vtb + (size_t)dd2 * 288 + k] = tile[kq][dd2];
        }
        __syncthreads();
    }
}

// ---------------- MFMA flash attention: block per (b,h), 4 waves x 16 q-rows ----------------
__global__ __launch_bounds__(256) void attn_mfma(
    const ushort* __restrict__ Q, const ushort* __restrict__ K,
    const ushort* __restrict__ Vt, ushort* __restrict__ O)
{
    const int h = blockIdx.x, b = blockIdx.y;
    const int t = threadIdx.x, lane = t & 63, w = t >> 6;
    const int lg = lane >> 4, lr = lane & 15;
    __shared__ ushort Pl[4][16][296];

    const size_t qkbase = ((size_t)b * SP) * DD + (size_t)h * DKK;
    const size_t vtbase = (size_t)(b * HH + h) * 64 * 288;

    #pragma unroll
    for (int i = 0; i < 4; ++i) Pl[w][lr][272 + lg * 4 + i] = 0;

    for (int p = 0; p < 5; ++p) {
        const int q0 = p * 64 + w * 16;
        const int qr = min(q0 + lr, SP - 1);
        bf16x8 aq0 = *reinterpret_cast<const bf16x8*>(&Q[qkbase + (size_t)qr * DD + lg * 8]);
        bf16x8 aq1 = *reinterpret_cast<const bf16x8*>(&Q[qkbase + (size_t)qr * DD + 32 + lg * 8]);

        f32x4 sc[17];
        #pragma unroll
        for (int n = 0; n < 17; ++n) {
            const int kr = min(n * 16 + lr, SP - 1);
            const ushort* kp = &K[qkbase + (size_t)kr * DD + lg * 8];
            bf16x8 bk0 = *reinterpret_cast<const bf16x8*>(kp);
            bf16x8 bk1 = *reinterpret_cast<const bf16x8*>(kp + 32);
            f32x4 a = (f32x4){0.f, 0.f, 0.f, 0.f};
            a = __builtin_amdgcn_mfma_f32_16x16x32_bf16(aq0, bk0, a, 0, 0, 0);
            a = __builtin_amdgcn_mfma_f32_16x16x32_bf16(aq1, bk1, a, 0, 0, 0);
            sc[n] = a;
        }

        float rmax[4] = {-1e30f, -1e30f, -1e30f, -1e30f};
        #pragma unroll
        for (int n = 0; n < 17; ++n) {
            const int kcol = n * 16 + lr;
            if (kcol >= SP) {
                sc[n] = (f32x4){-1e30f, -1e30f, -1e30f, -1e30f};
            } else {
                sc[n] *= 0.125f;
            }
            #pragma unroll
            for (int j = 0; j < 4; ++j) rmax[j] = fmaxf(rmax[j], sc[n][j]);
        }
        #pragma unroll
        for (int msk = 1; msk <= 8; msk <<= 1)
            #pragma unroll
            for (int j = 0; j < 4; ++j)
                rmax[j] = fmaxf(rmax[j], __shfl_xor(rmax[j], msk, 64));

        float rsum[4] = {0.f, 0.f, 0.f, 0.f};
        #pragma unroll
        for (int n = 0; n < 17; ++n) {
            #pragma unroll
            for (int j = 0; j < 4; ++j) {
                const float e = __expf(sc[n][j] - rmax[j]);
                rsum[j] += e;
                Pl[w][lg * 4 + j][n * 16 + lr] = f2bf(e);
            }
        }
        #pragma unroll
        for (int msk = 1; msk <= 8; msk <<= 1)
            #pragma unroll
            for (int j = 0; j < 4; ++j)
                rsum[j] += __shfl_xor(rsum[j], msk, 64);

        __syncthreads();

        f32x4 o[4];
        #pragma unroll
        for (int dn = 0; dn < 4; ++dn) o[dn] = (f32x4){0.f, 0.f, 0.f, 0.f};
        #pragma unroll
        for (int kb = 0; kb < 9; ++kb) {
            bf16x8 pa = *reinterpret_cast<const bf16x8*>(&Pl[w][lr][kb * 32 + lg * 8]);
            #pragma unroll
            for (int dn = 0; dn < 4; ++dn) {
                bf16x8 bv = *reinterpret_cast<const bf16x8*>(
                    &Vt[vtbase + (size_t)(dn * 16 + lr) * 288 + kb * 32 + lg * 8]);
                o[dn] = __builtin_amdgcn_mfma_f32_16x16x32_bf16(pa, bv, o[dn], 0, 0, 0);
            }
        }

        float rinv[4];
        #pragma unroll
        for (int j = 0; j < 4; ++j) rinv[j] = 1.f / rsum[j];
        #pragma unroll
        for (int dn = 0; dn < 4; ++dn) {
            #pragma unroll
            for (int j = 0; j < 4; ++j) {
                const int q = q0 + lg * 4 + j;
                if (q < SP)
                    O[qkbase + (size_t)q * DD + dn * 16 + lr] = f2bf(o[dn][j] * rinv[j]);
            }
        }
        __syncthreads();
    }
}

// ---------------- h = LayerNorm(h + r) * g + b; writes f32 h and bf16 hb ----------------
__global__ __launch_bounds__(256) void add_ln_kernel(
    float* __restrict__ h, ushort* __restrict__ hb, const ushort* __restrict__ r,
    const float* __restrict__ g, const float* __restrict__ bta)
{
    const int row = blockIdx.x;
    const int t = threadIdx.x;
    __shared__ float red4[4];
    float* hp = h + (size_t)row * DD;
    ushort* hbp = hb + (size_t)row * DD;
    const ushort* rp = r + (size_t)row * DD;
    const float x0 = hp[t]       + bf2f(rp[t]);
    const float x1 = hp[t + 256] + bf2f(rp[t + 256]);
    const float x2 = hp[t + 512] + bf2f(rp[t + 512]);
    const float s = blk_reduce<false>(x0 + x1 + x2, red4);
    const float mu = s * (1.f / 768.f);
    const float d0 = x0 - mu, d1 = x1 - mu, d2 = x2 - mu;
    const float v = blk_reduce<false>(d0 * d0 + d1 * d1 + d2 * d2, red4);
    const float inv = rsqrtf(v * (1.f / 768.f) + 1e-6f);
    const float y0 = d0 * inv * g[t]       + bta[t];
    const float y1 = d1 * inv * g[t + 256] + bta[t + 256];
    const float y2 = d2 * inv * g[t + 512] + bta[t + 512];
    hp[t]       = y0;  hbp[t]       = f2bf(y0);
    hp[t + 256] = y1;  hbp[t + 256] = f2bf(y1);
    hp[t + 512] = y2;  hbp[t + 512] = f2bf(y2);
}

// ---------------- final outputs ----------------
__global__ __launch_bounds__(256) void out_copy_kernel(
    const float* __restrict__ h, float* __restrict__ agg, float* __restrict__ pred)
{
    const int sf = blockIdx.x;
    const int b = blockIdx.y;
    const int t = threadIdx.x;
    const float* hp = h + ((size_t)b * SP + sf) * DD;
    if (sf == 0) {
        #pragma unroll
        for (int i = 0; i < 3; ++i) agg[(size_t)b * DD + t + 256 * i] = hp[t + 256 * i];
    } else {
        float* pp = pred + ((size_t)(b * SS + sf - 1)) * DD;
        #pragma unroll
        for (int i = 0; i < 3; ++i) pp[t + 256 * i] = hp[t + 256 * i];
    }
}

// ---------------- host launch ----------------
extern "C" void kernel_launch(void* const* d_in, const int* in_sizes, int n_in,
                              void* d_out, int out_size, void* d_ws, size_t ws_size,
                              hipStream_t stream)
{
    const float* inputs   = (const float*)d_in[0];
    const float* rnd3     = (const float*)d_in[1];
    const int*   perm     = (const int*)d_in[2];
    const float* conv_w   = (const float*)d_in[3];
    const float* conv_b   = (const float*)d_in[4];
    const float* pos_emb  = (const float*)d_in[5];
    const float* mask_tok = (const float*)d_in[6];
    const float* agg_tok  = (const float*)d_in[7];
    const float* wq = (const float*)d_in[8];
    const float* bq = (const float*)d_in[9];
    const float* wk = (const float*)d_in[10];
    const float* bk = (const float*)d_in[11];
    const float* wv = (const float*)d_in[12];
    const float* bv = (const float*)d_in[13];
    const float* wo = (const float*)d_in[14];
    const float* bo = (const float*)d_in[15];
    const float* ln1_g = (const float*)d_in[16];
    const float* ln1_b = (const float*)d_in[17];
    const float* w1 = (const float*)d_in[18];
    const float* b1 = (const float*)d_in[19];
    const float* w2 = (const float*)d_in[20];
    const float* b2 = (const float*)d_in[21];
    const float* ln2_g = (const float*)d_in[22];
    const float* ln2_b = (const float*)d_in[23];

    float* out = (float*)d_out;
    float* agg_out  = out;
    float* pred_out = out + 49152;
    float* mask_out = out + 49152 + 12582912;
    float* emb_out  = out + 49152 + 12582912 + 16384;

    // bf16 shadow of h lives in the pred region of d_out (free until out_copy;
    // needs MPAD*768*2 = 25.4 MB <= 50.3 MB region)
    ushort* hb = (ushort*)pred_out;

    // ---- workspace (~210 MB) ----
    // h f32 (ROWS*DD) | qb kb vb ob (bf16, MPAD rows each; FFN mid aliases all 4;
    // conv bf16-input aliases qb) | vt 28.3MB (rbuf aliases it) | bf16 weights
    char* base = (char*)d_ws;
    float*  h    = (float*)base;
    ushort* qb   = (ushort*)(base + RB * 4);
    ushort* kb   = qb + PRB;
    ushort* vb   = kb + PRB;
    ushort* ob   = vb + PRB;
    ushort* mid  = qb;                        // MPAD*FF == 4*PRB
    ushort* inbf = qb;                        // conv A scratch (dead before qb used)
    ushort* vt   = ob + PRB;                  // 768*64*288 = 14,155,776
    ushort* rbuf = vt;                        // PRB <= vt size
    ushort* wptr = vt + (size_t)768 * 64 * 288;

    ushort* convT = wptr;                          wptr += (size_t)DD * 512;
    ushort* wqT[2]; ushort* wkT[2]; ushort* wvT[2]; ushort* woT[2];
    ushort* w1T[2]; ushort* w2T[2];
    for (int l = 0; l < 2; ++l) {
        wqT[l] = wptr; wptr += (size_t)DD * DD;
        wkT[l] = wptr; wptr += (size_t)DD * DD;
        wvT[l] = wptr; wptr += (size_t)DD * DD;
        woT[l] = wptr; wptr += (size_t)DD * DD;
        w1T[l] = wptr; wptr += (size_t)DD * FF;
        w2T[l] = wptr; wptr += (size_t)FF * DD;
    }

    const dim3 blk(256);

    // 0. input + weight conversions
    conv_in_bf_kernel<<<dim3((MCONV * 512) / 1024), blk, 0, stream>>>(inputs, inbf);
    wt_kernel<<<dim3(512 / 32, DD / 32), blk, 0, stream>>>(conv_w, convT, 512, DD);
    for (int l = 0; l < 2; ++l) {
        wt_kernel<<<dim3(DD / 32, DD / 32), blk, 0, stream>>>(wq + (size_t)l*DD*DD, wqT[l], DD, DD);
        wt_kernel<<<dim3(DD / 32, DD / 32), blk, 0, stream>>>(wk + (size_t)l*DD*DD, wkT[l], DD, DD);
        wt_kernel<<<dim3(DD / 32, DD / 32), blk, 0, stream>>>(wv + (size_t)l*DD*DD, wvT[l], DD, DD);
        wt_kernel<<<dim3(DD / 32, DD / 32), blk, 0, stream>>>(wo + (size_t)l*DD*DD, woT[l], DD, DD);
        wt_kernel<<<dim3(DD / 32, FF / 32), blk, 0, stream>>>(w1 + (size_t)l*DD*FF, w1T[l], DD, FF);
        wt_kernel<<<dim3(FF / 32, DD / 32), blk, 0, stream>>>(w2 + (size_t)l*FF*DD, w2T[l], FF, DD);
    }

    // 1. conv as GEMM -> embeddings (f32, direct to d_out). M=16384, N=768, K=512.
    gemm128<false, false><<<dim3(DD / 128, MCONV / 128), blk, 0, stream>>>(
        inbf, convT, conv_b, emb_out, MCONV, DD, 512);

    // 2. build h (f32 + bf16 shadow) + mask_pos
    build_h_kernel<<<dim3(SP, BB), blk, 0, stream>>>(
        emb_out, rnd3, perm, pos_emb, mask_tok, agg_tok, h, hb, mask_out);

    // 3. transformer layers
    for (int l = 0; l < 2; ++l) {
        gemm128<true, false><<<dim3(DD / 128, MPAD / 128), blk, 0, stream>>>(
            hb, wqT[l], bq + l * DD, qb, MPAD, DD, DD);
        gemm128<true, false><<<dim3(DD / 128, MPAD / 128), blk, 0, stream>>>(
            hb, wkT[l], bk + l * DD, kb, MPAD, DD, DD);
        gemm128<true, false><<<dim3(DD / 128, MPAD / 128), blk, 0, stream>>>(
            hb, wvT[l], bv + l * DD, vb, MPAD, DD, DD);

        vt_kernel<<<dim3(BB * HH), blk, 0, stream>>>(vb, vt);
        attn_mfma<<<dim3(HH, BB), blk, 0, stream>>>(qb, kb, vt, ob);

        // O-projection -> rbuf (aliases vt, dead now)
        gemm128<true, false><<<dim3(DD / 128, MPAD / 128), blk, 0, stream>>>(
            ob, woT[l], bo + l * DD, rbuf, MPAD, DD, DD);

        add_ln_kernel<<<dim3(ROWS), blk, 0, stream>>>(
            h, hb, rbuf, ln1_g + l * DD, ln1_b + l * DD);

        // FFN (mid aliases q/k/v/o — dead here)
        gemm128<true, true><<<dim3(FF / 128, MPAD / 128), blk, 0, stream>>>(
            hb, w1T[l], b1 + l * FF, mid, MPAD, FF, DD);
        gemm128<true, false><<<dim3(DD / 128, MPAD / 128), blk, 0, stream>>>(
            mid, w2T[l], b2 + l * DD, rbuf, MPAD, DD, FF);

        add_ln_kernel<<<dim3(ROWS), blk, 0, stream>>>(
            h, hb, rbuf, ln2_g + l * DD, ln2_b + l * DD);
    }

    // 4. outputs (pred overwrites the hb scratch)
    out_copy_kernel<<<dim3(SP, BB), blk, 0, stream>>>(h, agg_out, pred_out);
}

// Round 7
// 1371.113 us; speedup vs baseline: 6.1841x; 1.1665x over previous
//
#include <hip/hip_runtime.h>
#include <hip/hip_bf16.h>
#include <math.h>

// Problem constants
#define BB 64
#define SS 256
#define SP 257           // S+1
#define DD 768
#define FF 3072
#define HH 12
#define DKK 64
#define ROWS (BB*SP)     // 16448 = 257*64
#define MPAD 16512       // 129*128
#define MCONV (BB*SS)    // 16384 = 128*128
#define RB ((size_t)ROWS * DD)     // 12,632,064
#define PRB ((size_t)MPAD * DD)    // 12,681,216

typedef short bf16x8 __attribute__((ext_vector_type(8)));
typedef float f32x4 __attribute__((ext_vector_type(4)));
typedef unsigned short ushort8v __attribute__((ext_vector_type(8)));

// ---------------- bf16 helpers ----------------
__device__ __forceinline__ ushort f2bf(float x) {
    union { __hip_bfloat16 h; ushort u; } c;
    c.h = __float2bfloat16(x);
    return c.u;
}
__device__ __forceinline__ float bf2f(ushort u) {
    union { __hip_bfloat16 h; ushort u; } c;
    c.u = u;
    return __bfloat162float(c.h);
}

// gelu(tanh approx) via sigmoid identity: 0.5*(1+tanh(u)) = 1/(1+e^{-2u})
__device__ __forceinline__ float gelu_fast(float x) {
    const float u = x * (1.0f + 0.044715f * x * x);  // x + 0.044715 x^3
    return x / (1.0f + __expf(-1.5957691216057308f * u));
}

// async global->LDS, 16B per lane; LDS arg must be wave-uniform base (HW adds lane*16)
__device__ __forceinline__ void gload16(const ushort* g, ushort* l) {
    __builtin_amdgcn_global_load_lds(
        (__attribute__((address_space(1))) void*)(g),
        (__attribute__((address_space(3))) void*)(l), 16, 0, 0);
}

template <bool IS_MAX>
__device__ __forceinline__ float blk_reduce(float v, float* red4) {
    #pragma unroll
    for (int o = 32; o > 0; o >>= 1) {
        float other = __shfl_down(v, o, 64);
        v = IS_MAX ? fmaxf(v, other) : (v + other);
    }
    __syncthreads();
    if ((threadIdx.x & 63) == 0) red4[threadIdx.x >> 6] = v;
    __syncthreads();
    if (IS_MAX) return fmaxf(fmaxf(red4[0], red4[1]), fmaxf(red4[2], red4[3]));
    return red4[0] + red4[1] + red4[2] + red4[3];
}

// ---------------- inputs f32 -> bf16 (conv A) ----------------
__global__ __launch_bounds__(256) void conv_in_bf_kernel(
    const float* __restrict__ in, ushort* __restrict__ out)
{
    const size_t i = ((size_t)blockIdx.x * 256 + threadIdx.x) * 4;
    float4 v = *reinterpret_cast<const float4*>(&in[i]);
    ushort4 o;
    o.x = f2bf(v.x); o.y = f2bf(v.y); o.z = f2bf(v.z); o.w = f2bf(v.w);
    *reinterpret_cast<ushort4*>(&out[i]) = o;
}

// ---------------- weight transpose + f32->bf16: W[K][N] -> Wt[N][K] ----------------
__global__ __launch_bounds__(256) void wt_kernel(
    const float* __restrict__ W, ushort* __restrict__ Wt, int K, int N)
{
    __shared__ float tile[32][33];
    const int k0 = blockIdx.x * 32, n0 = blockIdx.y * 32;
    const int t = threadIdx.x;
    {
        const int r = t >> 3, c4 = (t & 7) * 4;
        float4 v = *reinterpret_cast<const float4*>(&W[(size_t)(k0 + r) * N + n0 + c4]);
        tile[r][c4 + 0] = v.x; tile[r][c4 + 1] = v.y;
        tile[r][c4 + 2] = v.z; tile[r][c4 + 3] = v.w;
    }
    __syncthreads();
    {
        const int n = t >> 3, k4 = (t & 7) * 4;
        ushort4 o;
        o.x = f2bf(tile[k4 + 0][n]); o.y = f2bf(tile[k4 + 1][n]);
        o.z = f2bf(tile[k4 + 2][n]); o.w = f2bf(tile[k4 + 3][n]);
        *reinterpret_cast<ushort4*>(&Wt[(size_t)(n0 + n) * K + k0 + k4]) = o;
    }
}

// ---------------- gemm_pipe: C[M,N] = A[M,K] @ Bt[N,K]^T + bias (+gelu) ----------
// 128x128 tile, BK=32, 4 LDS slots, counted vmcnt(8) pipeline (stage t+3 while
// computing t), XOR bank-swizzle (slot ^= row&3) as involution on global source
// + ds_read, setprio around MFMA. 256 thr = 4 waves (2x2), wave -> 64x64.
// A,Bt bf16 row-major; M%128==0, N%128==0.
template <int K, bool C_BF16, bool GELU>
__global__ __launch_bounds__(256, 2) void gemm_pipe(
    const ushort* __restrict__ A, const ushort* __restrict__ Bt,
    const float* __restrict__ bias, void* __restrict__ Cp,
    int M, int N)
{
    constexpr int NT = K / 32;   // >= 16 for all our shapes
    __shared__ ushort lds[4][2][4096];   // [slot][op A/B][128 rows x 32 cols] = 64 KB
    const int tid = threadIdx.x;
    const int lane = tid & 63, w = tid >> 6;
    const int wr = w & 1, wc = w >> 1;
    const int lg = lane >> 4, lr = lane & 15;
    const int row0 = blockIdx.y * 128, col0 = blockIdx.x * 128;

    f32x4 acc[4][4];
    #pragma unroll
    for (int m = 0; m < 4; ++m)
        #pragma unroll
        for (int n = 0; n < 4; ++n)
            acc[m][n] = (f32x4){0.f, 0.f, 0.f, 0.f};

    // --- staging geometry: per tile each thread issues 2 A-loads + 2 B-loads.
    // Linear LDS 16B-slot s = i*256 + tid -> row = s>>2, kslot = s&3.
    // Swizzle involution: data (row, kg) lands at kslot = kg ^ (row&3),
    // so the linear-dest load i reads global kg = (tid&3) ^ (row&3).
    const int s_row0 = tid >> 2;            // rows 0..63
    const int s_row1 = 64 + (tid >> 2);     // rows 64..127
    const int kg0 = ((tid & 3) ^ (s_row0 & 3)) * 8;
    const int kg1 = ((tid & 3) ^ (s_row1 & 3)) * 8;
    const ushort* Ab = A + (size_t)row0 * K;
    const ushort* Bb = Bt + (size_t)col0 * K;

    auto STAGE = [&](int slot, int t) {
        const int k0 = t * 32;
        gload16(Ab + (size_t)s_row0 * K + k0 + kg0, &lds[slot][0][w * 512]);
        gload16(Ab + (size_t)s_row1 * K + k0 + kg1, &lds[slot][0][2048 + w * 512]);
        gload16(Bb + (size_t)s_row0 * K + k0 + kg0, &lds[slot][1][w * 512]);
        gload16(Bb + (size_t)s_row1 * K + k0 + kg1, &lds[slot][1][2048 + w * 512]);
    };

    // --- fragment reads: row r, k-group lg -> swizzled k-slot lg ^ (r&3).
    // r&3 == lr&3 for all frag rows (wr*64, wc*64, m*16 are multiples of 4).
    const int swz = (lg ^ (lr & 3)) * 8;

    auto COMPUTE = [&](int slot) {
        bf16x8 af[4], bfr[4];
        #pragma unroll
        for (int m = 0; m < 4; ++m)
            af[m] = *reinterpret_cast<const bf16x8*>(
                &lds[slot][0][(wr * 64 + m * 16 + lr) * 32 + swz]);
        #pragma unroll
        for (int n = 0; n < 4; ++n)
            bfr[n] = *reinterpret_cast<const bf16x8*>(
                &lds[slot][1][(wc * 64 + n * 16 + lr) * 32 + swz]);
        __builtin_amdgcn_s_setprio(1);
        #pragma unroll
        for (int m = 0; m < 4; ++m)
            #pragma unroll
            for (int n = 0; n < 4; ++n)
                acc[m][n] = __builtin_amdgcn_mfma_f32_16x16x32_bf16(
                    af[m], bfr[n], acc[m][n], 0, 0, 0);
        __builtin_amdgcn_s_setprio(0);
    };

    // --- prologue: stage tiles 0..2 into slots 0..2; wait tile 0 (12 issued,
    // vmcnt(8) -> 4 oldest done = tile 0).
    STAGE(0, 0); STAGE(1, 1); STAGE(2, 2);
    asm volatile("s_waitcnt vmcnt(8)" ::: "memory");
    __builtin_amdgcn_s_barrier();
    asm volatile("" ::: "memory");

    // --- main loop: boundary t has tiles t+2,t+3 in flight (8 loads);
    // vmcnt(8) forces tile t+1 (older) complete. Slot (t+3)&3 was last read
    // at iter t-1, protected by that boundary's barrier.
    #pragma unroll 4
    for (int t = 0; t < NT - 3; ++t) {
        STAGE((t + 3) & 3, t + 3);
        COMPUTE(t & 3);
        asm volatile("s_waitcnt vmcnt(8)" ::: "memory");
        __builtin_amdgcn_s_barrier();
        asm volatile("" ::: "memory");
    }
    COMPUTE((NT - 3) & 3);
    asm volatile("s_waitcnt vmcnt(4)" ::: "memory");   // tile NT-2 landed
    __builtin_amdgcn_s_barrier();
    asm volatile("" ::: "memory");
    COMPUTE((NT - 2) & 3);
    asm volatile("s_waitcnt vmcnt(0)" ::: "memory");   // tile NT-1 landed
    __builtin_amdgcn_s_barrier();
    asm volatile("" ::: "memory");
    COMPUTE((NT - 1) & 3);

    // --- epilogue: C/D layout col=lane&15, row=(lane>>4)*4+j (verified r3/r5)
    #pragma unroll
    for (int m = 0; m < 4; ++m) {
        #pragma unroll
        for (int n = 0; n < 4; ++n) {
            const int col = col0 + wc * 64 + n * 16 + lr;
            const float bcol = bias[col];
            #pragma unroll
            for (int j = 0; j < 4; ++j) {
                const int row = row0 + wr * 64 + m * 16 + lg * 4 + j;
                float v = acc[m][n][j] + bcol;
                if (GELU) v = gelu_fast(v);
                if (C_BF16) ((ushort*)Cp)[(size_t)row * N + col] = f2bf(v);
                else        ((float*)Cp)[(size_t)row * N + col] = v;
            }
        }
    }
}

// ---------------- build h (f32 + bf16 shadow) ----------------
__global__ __launch_bounds__(256) void build_h_kernel(
    const float* __restrict__ emb, const float* __restrict__ rnd3,
    const int* __restrict__ perm, const float* __restrict__ pos_emb,
    const float* __restrict__ mask_tok, const float* __restrict__ agg_tok,
    float* __restrict__ h, ushort* __restrict__ hb, float* __restrict__ mask_pos)
{
    const int sf = blockIdx.x;
    const int b = blockIdx.y;
    const int t = threadIdx.x;
    const size_t ro = ((size_t)b * SP + sf) * DD;
    float* hrow = h + ro;
    ushort* hbrow = hb + ro;
    if (sf == 0) {
        #pragma unroll
        for (int i = 0; i < 3; ++i) {
            const float v = agg_tok[t + 256 * i];
            hrow[t + 256 * i] = v;
            hbrow[t + 256 * i] = f2bf(v);
        }
        return;
    }
    const int s = sf - 1;
    const int idx = b * SS + s;
    const float r0 = rnd3[idx * 3 + 0];
    const float r1 = rnd3[idx * 3 + 1];
    const float r2 = rnd3[idx * 3 + 2];
    const bool sel = (r0 <= 0.2f);
    const float m  = (sel && r1 <= 0.8f) ? 1.f : 0.f;
    const float rn = (sel && r1 > 0.8f && r2 <= 0.5f) ? 1.f : 0.f;
    const float nt = (sel && r1 > 0.8f && r2 > 0.5f) ? 1.f : 0.f;
    if (t == 0) mask_pos[idx] = m + rn + nt;
    const int p = perm[idx];
    const float* xrow = emb + (size_t)idx * DD;
    const float* srow = emb + (size_t)p * DD;
    const float keep = 1.f - m - rn;
    #pragma unroll
    for (int i = 0; i < 3; ++i) {
        const int c = t + 256 * i;
        const float v = xrow[c] * keep + mask_tok[c] * m + srow[c] * rn + pos_emb[s * DD + c];
        hrow[c] = v;
        hbrow[c] = f2bf(v);
    }
}

// ---------------- V transpose per (b,h): V[257][64] -> Vt[64][288] (zero-padded) ----------------
__global__ __launch_bounds__(256) void vt_kernel(
    const ushort* __restrict__ V, ushort* __restrict__ Vt)
{
    const int bh = blockIdx.x;
    const int b = bh / HH, h = bh % HH;
    const int t = threadIdx.x;
    __shared__ ushort tile[64][65];
    const size_t vtb = (size_t)bh * 64 * 288;
    const int d = t & 63, kk = t >> 6;
    const int kq = t & 63, dg = t >> 6;
    for (int kt = 0; kt < 5; ++kt) {
        #pragma unroll
        for (int i = 0; i < 16; ++i) {
            const int r = kk + 4 * i;
            const int kg = kt * 64 + r;
            tile[r][d] = (kg < SP) ? V[((size_t)b * SP + kg) * DD + h * 64 + d] : (ushort)0;
        }
        __syncthreads();
        #pragma unroll
        for (int i = 0; i < 16; ++i) {
            const int dd2 = dg + 4 * i;
            const int k = kt * 64 + kq;
            if (k < 288) Vt[vtb + (size_t)dd2 * 288 + k] = tile[kq][dd2];
        }
        __syncthreads();
    }
}

// ---------------- MFMA flash attention: block per (b,h), 4 waves x 16 q-rows ----------------
__global__ __launch_bounds__(256) void attn_mfma(
    const ushort* __restrict__ Q, const ushort* __restrict__ K,
    const ushort* __restrict__ Vt, ushort* __restrict__ O)
{
    const int h = blockIdx.x, b = blockIdx.y;
    const int t = threadIdx.x, lane = t & 63, w = t >> 6;
    const int lg = lane >> 4, lr = lane & 15;
    __shared__ ushort Pl[4][16][296];

    const size_t qkbase = ((size_t)b * SP) * DD + (size_t)h * DKK;
    const size_t vtbase = (size_t)(b * HH + h) * 64 * 288;

    #pragma unroll
    for (int i = 0; i < 4; ++i) Pl[w][lr][272 + lg * 4 + i] = 0;

    for (int p = 0; p < 5; ++p) {
        const int q0 = p * 64 + w * 16;
        const int qr = min(q0 + lr, SP - 1);
        bf16x8 aq0 = *reinterpret_cast<const bf16x8*>(&Q[qkbase + (size_t)qr * DD + lg * 8]);
        bf16x8 aq1 = *reinterpret_cast<const bf16x8*>(&Q[qkbase + (size_t)qr * DD + 32 + lg * 8]);

        f32x4 sc[17];
        #pragma unroll
        for (int n = 0; n < 17; ++n) {
            const int kr = min(n * 16 + lr, SP - 1);
            const ushort* kp = &K[qkbase + (size_t)kr * DD + lg * 8];
            bf16x8 bk0 = *reinterpret_cast<const bf16x8*>(kp);
            bf16x8 bk1 = *reinterpret_cast<const bf16x8*>(kp + 32);
            f32x4 a = (f32x4){0.f, 0.f, 0.f, 0.f};
            a = __builtin_amdgcn_mfma_f32_16x16x32_bf16(aq0, bk0, a, 0, 0, 0);
            a = __builtin_amdgcn_mfma_f32_16x16x32_bf16(aq1, bk1, a, 0, 0, 0);
            sc[n] = a;
        }

        float rmax[4] = {-1e30f, -1e30f, -1e30f, -1e30f};
        #pragma unroll
        for (int n = 0; n < 17; ++n) {
            const int kcol = n * 16 + lr;
            if (kcol >= SP) {
                sc[n] = (f32x4){-1e30f, -1e30f, -1e30f, -1e30f};
            } else {
                sc[n] *= 0.125f;
            }
            #pragma unroll
            for (int j = 0; j < 4; ++j) rmax[j] = fmaxf(rmax[j], sc[n][j]);
        }
        #pragma unroll
        for (int msk = 1; msk <= 8; msk <<= 1)
            #pragma unroll
            for (int j = 0; j < 4; ++j)
                rmax[j] = fmaxf(rmax[j], __shfl_xor(rmax[j], msk, 64));

        float rsum[4] = {0.f, 0.f, 0.f, 0.f};
        #pragma unroll
        for (int n = 0; n < 17; ++n) {
            #pragma unroll
            for (int j = 0; j < 4; ++j) {
                const float e = __expf(sc[n][j] - rmax[j]);
                rsum[j] += e;
                Pl[w][lg * 4 + j][n * 16 + lr] = f2bf(e);
            }
        }
        #pragma unroll
        for (int msk = 1; msk <= 8; msk <<= 1)
            #pragma unroll
            for (int j = 0; j < 4; ++j)
                rsum[j] += __shfl_xor(rsum[j], msk, 64);

        __syncthreads();

        f32x4 o[4];
        #pragma unroll
        for (int dn = 0; dn < 4; ++dn) o[dn] = (f32x4){0.f, 0.f, 0.f, 0.f};
        #pragma unroll
        for (int kb = 0; kb < 9; ++kb) {
            bf16x8 pa = *reinterpret_cast<const bf16x8*>(&Pl[w][lr][kb * 32 + lg * 8]);
            #pragma unroll
            for (int dn = 0; dn < 4; ++dn) {
                bf16x8 bv = *reinterpret_cast<const bf16x8*>(
                    &Vt[vtbase + (size_t)(dn * 16 + lr) * 288 + kb * 32 + lg * 8]);
                o[dn] = __builtin_amdgcn_mfma_f32_16x16x32_bf16(pa, bv, o[dn], 0, 0, 0);
            }
        }

        float rinv[4];
        #pragma unroll
        for (int j = 0; j < 4; ++j) rinv[j] = 1.f / rsum[j];
        #pragma unroll
        for (int dn = 0; dn < 4; ++dn) {
            #pragma unroll
            for (int j = 0; j < 4; ++j) {
                const int q = q0 + lg * 4 + j;
                if (q < SP)
                    O[qkbase + (size_t)q * DD + dn * 16 + lr] = f2bf(o[dn][j] * rinv[j]);
            }
        }
        __syncthreads();
    }
}

// ---------------- h = LayerNorm(h + r) * g + b; writes f32 h and bf16 hb ----------------
__global__ __launch_bounds__(256) void add_ln_kernel(
    float* __restrict__ h, ushort* __restrict__ hb, const ushort* __restrict__ r,
    const float* __restrict__ g, const float* __restrict__ bta)
{
    const int row = blockIdx.x;
    const int t = threadIdx.x;
    __shared__ float red4[4];
    float* hp = h + (size_t)row * DD;
    ushort* hbp = hb + (size_t)row * DD;
    const ushort* rp = r + (size_t)row * DD;
    const float x0 = hp[t]       + bf2f(rp[t]);
    const float x1 = hp[t + 256] + bf2f(rp[t + 256]);
    const float x2 = hp[t + 512] + bf2f(rp[t + 512]);
    const float s = blk_reduce<false>(x0 + x1 + x2, red4);
    const float mu = s * (1.f / 768.f);
    const float d0 = x0 - mu, d1 = x1 - mu, d2 = x2 - mu;
    const float v = blk_reduce<false>(d0 * d0 + d1 * d1 + d2 * d2, red4);
    const float inv = rsqrtf(v * (1.f / 768.f) + 1e-6f);
    const float y0 = d0 * inv * g[t]       + bta[t];
    const float y1 = d1 * inv * g[t + 256] + bta[t + 256];
    const float y2 = d2 * inv * g[t + 512] + bta[t + 512];
    hp[t]       = y0;  hbp[t]       = f2bf(y0);
    hp[t + 256] = y1;  hbp[t + 256] = f2bf(y1);
    hp[t + 512] = y2;  hbp[t + 512] = f2bf(y2);
}

// ---------------- final outputs ----------------
__global__ __launch_bounds__(256) void out_copy_kernel(
    const float* __restrict__ h, float* __restrict__ agg, float* __restrict__ pred)
{
    const int sf = blockIdx.x;
    const int b = blockIdx.y;
    const int t = threadIdx.x;
    const float* hp = h + ((size_t)b * SP + sf) * DD;
    if (sf == 0) {
        #pragma unroll
        for (int i = 0; i < 3; ++i) agg[(size_t)b * DD + t + 256 * i] = hp[t + 256 * i];
    } else {
        float* pp = pred + ((size_t)(b * SS + sf - 1)) * DD;
        #pragma unroll
        for (int i = 0; i < 3; ++i) pp[t + 256 * i] = hp[t + 256 * i];
    }
}

// ---------------- host launch ----------------
extern "C" void kernel_launch(void* const* d_in, const int* in_sizes, int n_in,
                              void* d_out, int out_size, void* d_ws, size_t ws_size,
                              hipStream_t stream)
{
    const float* inputs   = (const float*)d_in[0];
    const float* rnd3     = (const float*)d_in[1];
    const int*   perm     = (const int*)d_in[2];
    const float* conv_w   = (const float*)d_in[3];
    const float* conv_b   = (const float*)d_in[4];
    const float* pos_emb  = (const float*)d_in[5];
    const float* mask_tok = (const float*)d_in[6];
    const float* agg_tok  = (const float*)d_in[7];
    const float* wq = (const float*)d_in[8];
    const float* bq = (const float*)d_in[9];
    const float* wk = (const float*)d_in[10];
    const float* bk = (const float*)d_in[11];
    const float* wv = (const float*)d_in[12];
    const float* bv = (const float*)d_in[13];
    const float* wo = (const float*)d_in[14];
    const float* bo = (const float*)d_in[15];
    const float* ln1_g = (const float*)d_in[16];
    const float* ln1_b = (const float*)d_in[17];
    const float* w1 = (const float*)d_in[18];
    const float* b1 = (const float*)d_in[19];
    const float* w2 = (const float*)d_in[20];
    const float* b2 = (const float*)d_in[21];
    const float* ln2_g = (const float*)d_in[22];
    const float* ln2_b = (const float*)d_in[23];

    float* out = (float*)d_out;
    float* agg_out  = out;
    float* pred_out = out + 49152;
    float* mask_out = out + 49152 + 12582912;
    float* emb_out  = out + 49152 + 12582912 + 16384;

    // bf16 shadow of h in the pred region (free until out_copy; 25.4MB <= 50.3MB)
    ushort* hb = (ushort*)pred_out;

    // ---- workspace (~210 MB) ----
    char* base = (char*)d_ws;
    float*  h    = (float*)base;
    ushort* qb   = (ushort*)(base + RB * 4);
    ushort* kb   = qb + PRB;
    ushort* vb   = kb + PRB;
    ushort* ob   = vb + PRB;
    ushort* mid  = qb;                        // MPAD*FF == 4*PRB
    ushort* inbf = qb;                        // conv A scratch (dead before qb used)
    ushort* vt   = ob + PRB;                  // 768*64*288 = 14,155,776
    ushort* rbuf = vt;                        // PRB <= vt size
    ushort* wptr = vt + (size_t)768 * 64 * 288;

    ushort* convT = wptr;                          wptr += (size_t)DD * 512;
    ushort* wqT[2]; ushort* wkT[2]; ushort* wvT[2]; ushort* woT[2];
    ushort* w1T[2]; ushort* w2T[2];
    for (int l = 0; l < 2; ++l) {
        wqT[l] = wptr; wptr += (size_t)DD * DD;
        wkT[l] = wptr; wptr += (size_t)DD * DD;
        wvT[l] = wptr; wptr += (size_t)DD * DD;
        woT[l] = wptr; wptr += (size_t)DD * DD;
        w1T[l] = wptr; wptr += (size_t)DD * FF;
        w2T[l] = wptr; wptr += (size_t)FF * DD;
    }

    const dim3 blk(256);

    // 0. input + weight conversions
    conv_in_bf_kernel<<<dim3((MCONV * 512) / 1024), blk, 0, stream>>>(inputs, inbf);
    wt_kernel<<<dim3(512 / 32, DD / 32), blk, 0, stream>>>(conv_w, convT, 512, DD);
    for (int l = 0; l < 2; ++l) {
        wt_kernel<<<dim3(DD / 32, DD / 32), blk, 0, stream>>>(wq + (size_t)l*DD*DD, wqT[l], DD, DD);
        wt_kernel<<<dim3(DD / 32, DD / 32), blk, 0, stream>>>(wk + (size_t)l*DD*DD, wkT[l], DD, DD);
        wt_kernel<<<dim3(DD / 32, DD / 32), blk, 0, stream>>>(wv + (size_t)l*DD*DD, wvT[l], DD, DD);
        wt_kernel<<<dim3(DD / 32, DD / 32), blk, 0, stream>>>(wo + (size_t)l*DD*DD, woT[l], DD, DD);
        wt_kernel<<<dim3(DD / 32, FF / 32), blk, 0, stream>>>(w1 + (size_t)l*DD*FF, w1T[l], DD, FF);
        wt_kernel<<<dim3(FF / 32, DD / 32), blk, 0, stream>>>(w2 + (size_t)l*FF*DD, w2T[l], FF, DD);
    }

    // 1. conv as GEMM -> embeddings (f32, direct to d_out). M=16384, N=768, K=512.
    gemm_pipe<512, false, false><<<dim3(DD / 128, MCONV / 128), blk, 0, stream>>>(
        inbf, convT, conv_b, emb_out, MCONV, DD);

    // 2. build h (f32 + bf16 shadow) + mask_pos
    build_h_kernel<<<dim3(SP, BB), blk, 0, stream>>>(
        emb_out, rnd3, perm, pos_emb, mask_tok, agg_tok, h, hb, mask_out);

    // 3. transformer layers
    for (int l = 0; l < 2; ++l) {
        gemm_pipe<768, true, false><<<dim3(DD / 128, MPAD / 128), blk, 0, stream>>>(
            hb, wqT[l], bq + l * DD, qb, MPAD, DD);
        gemm_pipe<768, true, false><<<dim3(DD / 128, MPAD / 128), blk, 0, stream>>>(
            hb, wkT[l], bk + l * DD, kb, MPAD, DD);
        gemm_pipe<768, true, false><<<dim3(DD / 128, MPAD / 128), blk, 0, stream>>>(
            hb, wvT[l], bv + l * DD, vb, MPAD, DD);

        vt_kernel<<<dim3(BB * HH), blk, 0, stream>>>(vb, vt);
        attn_mfma<<<dim3(HH, BB), blk, 0, stream>>>(qb, kb, vt, ob);

        // O-projection -> rbuf (aliases vt, dead now)
        gemm_pipe<768, true, false><<<dim3(DD / 128, MPAD / 128), blk, 0, stream>>>(
            ob, woT[l], bo + l * DD, rbuf, MPAD, DD);

        add_ln_kernel<<<dim3(ROWS), blk, 0, stream>>>(
            h, hb, rbuf, ln1_g + l * DD, ln1_b + l * DD);

        // FFN (mid aliases q/k/v/o — dead here)
        gemm_pipe<768, true, true><<<dim3(FF / 128, MPAD / 128), blk, 0, stream>>>(
            hb, w1T[l], b1 + l * FF, mid, MPAD, FF);
        gemm_pipe<3072, true, false><<<dim3(DD / 128, MPAD / 128), blk, 0, stream>>>(
            mid, w2T[l], b2 + l * DD, rbuf, MPAD, DD);

        add_ln_kernel<<<dim3(ROWS), blk, 0, stream>>>(
            h, hb, rbuf, ln2_g + l * DD, ln2_b + l * DD);
    }

    // 4. outputs (pred overwrites the hb scratch)
    out_copy_kernel<<<dim3(SP, BB), blk, 0, stream>>>(h, agg_out, pred_out);
}